// Round 10
// baseline (1094.416 us; speedup 1.0000x reference)
//
#include <hip/hip_runtime.h>
#include <hip/hip_bf16.h>
#include <stdint.h>

#define NTOK 8192
#define DM   1024
#define DH   2048
#define NE   16

// Persistent-worker geometry: 256 CUs x 3 blocks/CU (reg-limited). Per-XCD
// work queues + cross-XCD stealing (own queue first, then advance).
#define NWRK  768
#define QCAP1 2048   // worst case per XCD: 128 m-tiles * 16 panels
#define QCAP2 1024   // 128 m-tiles * 8 panels

typedef float  f32x4  __attribute__((ext_vector_type(4)));
typedef __bf16 bf16x8 __attribute__((ext_vector_type(8)));

__device__ __forceinline__ unsigned short f2bf(float f) {
  union { __bf16 b; unsigned short u; } c; c.b = (__bf16)f; return c.u;
}

__device__ __forceinline__ void glds16(const void* g, void* l) {
  __builtin_amdgcn_global_load_lds(
      (const __attribute__((address_space(1))) void*)g,
      (__attribute__((address_space(3))) void*)l, 16, 0, 0);
}

// ---------------- router: logits, top-2, softmax; x -> bf16; zero d_out.
__global__ __launch_bounds__(256) void router_kernel(
    const float* __restrict__ x, const float* __restrict__ Wg,
    unsigned short* __restrict__ xb, int* __restrict__ eidx,
    float* __restrict__ ewt, float* __restrict__ outz)
{
  const int lane = threadIdx.x & 63;
  const int wave = threadIdx.x >> 6;
  const int t = blockIdx.x * 4 + wave;
  const float* xr = x + (size_t)t * DM;

  float4 xv[4];
#pragma unroll
  for (int c = 0; c < 4; ++c)
    xv[c] = *(const float4*)(xr + c * 256 + lane * 4);

  unsigned short* xbr = xb + (size_t)t * DM;
#pragma unroll
  for (int c = 0; c < 4; ++c) {
    ushort4 u;
    u.x = f2bf(xv[c].x); u.y = f2bf(xv[c].y);
    u.z = f2bf(xv[c].z); u.w = f2bf(xv[c].w);
    *(ushort4*)(xbr + c * 256 + lane * 4) = u;
  }

  // zero the atomic target (replaces hipMemsetAsync; stream order
  // guarantees completion before GEMM2's atomics)
  {
    float4 z4 = {0.f, 0.f, 0.f, 0.f};
    float* orow = outz + (size_t)t * DM;
#pragma unroll
    for (int c = 0; c < 4; ++c)
      *(float4*)(orow + c * 256 + lane * 4) = z4;
  }

  float acc[NE];
#pragma unroll
  for (int e = 0; e < NE; ++e) acc[e] = 0.f;
#pragma unroll
  for (int e = 0; e < NE; ++e) {
#pragma unroll
    for (int c = 0; c < 4; ++c) {
      float4 wv = *(const float4*)(Wg + e * DM + c * 256 + lane * 4);
      acc[e] += xv[c].x * wv.x + xv[c].y * wv.y + xv[c].z * wv.z + xv[c].w * wv.w;
    }
  }
#pragma unroll
  for (int e = 0; e < NE; ++e) {
    float v = acc[e];
    v += __shfl_xor(v, 1);  v += __shfl_xor(v, 2);  v += __shfl_xor(v, 4);
    v += __shfl_xor(v, 8);  v += __shfl_xor(v, 16); v += __shfl_xor(v, 32);
    acc[e] = v;
  }
  if (lane == 0) {
    float v0 = -1e30f; int i0 = 0;
#pragma unroll
    for (int e = 0; e < NE; ++e) if (acc[e] > v0) { v0 = acc[e]; i0 = e; }
    float v1 = -1e30f; int i1 = 0;
#pragma unroll
    for (int e = 0; e < NE; ++e) if (e != i0 && acc[e] > v1) { v1 = acc[e]; i1 = e; }
    float p = expf(v1 - v0);
    float s = 1.f / (1.f + p);
    eidx[2 * t] = i0; eidx[2 * t + 1] = i1;
    ewt[2 * t] = s;   ewt[2 * t + 1] = p * s;
  }
}

// ---------------- fused plan + weight prep ----------------------------------
// Block 0 (1024 thr): plan. Blocks 1..4096: weight prep fp32 [E][K][N] ->
// bf16 [E][N][K], 4 64x64 tiles per block. plan's serial scan hides under
// the BW-bound transposes. wl1/wl2: expert-outer, m-half (h0 split), panel,
// m-in-half ordering; item (e<<16)|(mt<<8)|p.  [verified round-8 form]
__global__ __launch_bounds__(1024) void planprep_kernel(
    const int* __restrict__ eidx, const float* __restrict__ ewt,
    int* __restrict__ cnt, int* __restrict__ offv,
    int* __restrict__ tok, float* __restrict__ wtl,
    int* __restrict__ wl1, int* __restrict__ wl2,
    int* __restrict__ qn1, int* __restrict__ qn2,
    int* __restrict__ qc1, int* __restrict__ qc2,
    const float* __restrict__ W1, unsigned short* __restrict__ w1t,
    const float* __restrict__ W2, unsigned short* __restrict__ w2t)
{
  __shared__ float t[4][64][68];
  __shared__ int wcnt[16][NE];
  __shared__ int wbase[16][NE];
  __shared__ int offs[NE];
  __shared__ int s_nmt[NE];
  __shared__ int s_pnmt[NE + 1];

  if (blockIdx.x != 0) {
    // ---- weight prep: 4 tiles per 1024-thread block
    const int idx = blockIdx.x - 1;
    const int tg  = threadIdx.x >> 8;     // tile group 0..3
    const int t8  = threadIdx.x & 255;
    const float* W; unsigned short* WT; int K, N, tt, bx, by;
    if (idx < 2048) {
      W = W1; WT = w1t; K = DM; N = DH;
      tt = idx * 4 + tg;                  // 0..8191
      int r = tt & 511; bx = r & 31; by = r >> 5;
    } else {
      W = W2; WT = w2t; K = DH; N = DM;
      tt = (idx - 2048) * 4 + tg;
      int r = tt & 511; bx = r & 15; by = r >> 4;
    }
    const int bz = tt >> 9;
    const int k0 = by * 64, n0 = bx * 64;
    const int tr = t8 >> 2;
    const int tc = (t8 & 3) * 16;
    const float* src = W + ((size_t)bz * K + k0) * N + n0;
#pragma unroll
    for (int j = 0; j < 4; ++j) {
      float4 v = *(const float4*)(src + (size_t)tr * N + tc + j * 4);
      t[tg][tc + j * 4 + 0][tr] = v.x;
      t[tg][tc + j * 4 + 1][tr] = v.y;
      t[tg][tc + j * 4 + 2][tr] = v.z;
      t[tg][tc + j * 4 + 3][tr] = v.w;
    }
    __syncthreads();
    unsigned short* dst = WT + ((size_t)bz * N + n0) * K + k0;
#pragma unroll
    for (int j = 0; j < 4; ++j) {
      float4 v = *(const float4*)(&t[tg][tr][tc + j * 4]);
      ushort4 u;
      u.x = f2bf(v.x); u.y = f2bf(v.y); u.z = f2bf(v.z); u.w = f2bf(v.w);
      *(ushort4*)(dst + (size_t)tr * K + tc + j * 4) = u;
    }
    return;
  }

  // ---- plan (block 0, 1024 threads)
  const int tid  = threadIdx.x;
  const int wave = tid >> 6;
  const int lane = tid & 63;
  const unsigned long long below = (1ull << lane) - 1ull;

  // phase 1: cache pairs; per-wave per-expert counts via ballot
  int   pe[16];
  float pw[16];
  int   count[NE];
#pragma unroll
  for (int e = 0; e < NE; ++e) count[e] = 0;
#pragma unroll
  for (int r = 0; r < 16; ++r) {
    int p = wave * 1024 + r * 64 + lane;
    pe[r] = eidx[p];
    pw[r] = ewt[p];
#pragma unroll
    for (int e = 0; e < NE; ++e) {
      unsigned long long m = __ballot(pe[r] == e);
      count[e] += (int)__popcll(m);
    }
  }
  if (lane == 0) {
#pragma unroll
    for (int e = 0; e < NE; ++e) wcnt[wave][e] = count[e];
  }
  __syncthreads();

  // phase 2: thread 0 serial scan; offsets + tile geometry
  if (tid == 0) {
    int s = 0;
    s_pnmt[0] = 0;
    for (int e = 0; e < NE; ++e) {
      offs[e] = s;
      int tcnt = 0;
      for (int w = 0; w < 16; ++w) { wbase[w][e] = tcnt; tcnt += wcnt[w][e]; }
      cnt[e] = tcnt; offv[e] = s; s += tcnt;
      int nmt = (tcnt + 127) >> 7;
      s_nmt[e] = nmt;
      s_pnmt[e + 1] = s_pnmt[e] + nmt;
    }
    offv[NE] = s;
  }
  __syncthreads();

  // queue sizes + counter reset (one thread per XCD)
  if (tid < 8) {
    qn1[tid] = (s_nmt[tid] + s_nmt[tid + 8]) * 16;
    qn2[tid] = (s_nmt[tid] + s_nmt[tid + 8]) * 8;
    qc1[tid] = 0;
    qc2[tid] = 0;
  }

  // phase 2b: parallel dense queue fill (closed-form bijective positions)
  {
    const int totmt = s_pnmt[NE];
    const int T1 = totmt * 16;
    for (int i = tid; i < T1; i += 1024) {
      int gmt = i >> 4, p = i & 15;
      int e = 0;
      while (s_pnmt[e + 1] <= gmt) ++e;
      int mt  = gmt - s_pnmt[e];
      int nmt = s_nmt[e];
      int h0  = (nmt + 1) >> 1;   // m-half split: hot A slab stays bounded
      int pos_e = (mt < h0) ? (p * h0 + mt)
                            : (h0 * 16 + p * (nmt - h0) + (mt - h0));
      int xx   = e & 7;
      int base = (e < 8) ? 0 : s_nmt[e - 8] * 16;
      wl1[xx * QCAP1 + base + pos_e] = (e << 16) | (mt << 8) | p;
    }
    const int T2 = totmt * 8;
    for (int i = tid; i < T2; i += 1024) {
      int gmt = i >> 3, p = i & 7;
      int e = 0;
      while (s_pnmt[e + 1] <= gmt) ++e;
      int mt  = gmt - s_pnmt[e];
      int nmt = s_nmt[e];
      int h0  = (nmt + 1) >> 1;
      int pos_e = (mt < h0) ? (p * h0 + mt)
                            : (h0 * 8 + p * (nmt - h0) + (mt - h0));
      int xx   = e & 7;
      int base = (e < 8) ? 0 : s_nmt[e - 8] * 8;
      wl2[xx * QCAP2 + base + pos_e] = (e << 16) | (mt << 8) | p;
    }
  }

  // phase 3: rank + scatter tokens (deterministic)
  int run[NE];
#pragma unroll
  for (int e = 0; e < NE; ++e) run[e] = 0;
#pragma unroll
  for (int r = 0; r < 16; ++r) {
    int p = wave * 1024 + r * 64 + lane;
#pragma unroll
    for (int e = 0; e < NE; ++e) {
      unsigned long long m = __ballot(pe[r] == e);
      if (pe[r] == e) {
        int rank = (int)__popcll(m & below);
        int slot = offs[e] + wbase[wave][e] + run[e] + rank;
        tok[slot] = p >> 1;
        wtl[slot] = pw[r];
      }
      run[e] += (int)__popcll(m);
    }
  }
}

// ---------------- 128x128 gathered GEMM, BK=64, m97 2-barrier loop,
// persistent per-XCD workers + cross-XCD stealing (own queue first, then
// advance cursor; items commute — GEMM1 slots unique, GEMM2 atomic).
// Inner K-loop verbatim from the verified round-3/6/8 kernel.
// EPI=0: h = relu(acc+b1) -> bf16    EPI=1: atomicAdd(out, (acc+b2)*w)
template<int GATHER, int EPI, int KDIM, int NDIM, int QCAP>
__global__ __launch_bounds__(256, 3) void gemm_kernel(
    const unsigned short* __restrict__ Abase,
    const unsigned short* __restrict__ BT,
    const float* __restrict__ bias,
    const int* __restrict__ cnt, const int* __restrict__ offv,
    const int* __restrict__ tok, const float* __restrict__ wtl,
    const int* __restrict__ wl, const int* __restrict__ qn,
    int* __restrict__ qc, void* __restrict__ outp)
{
  __shared__ unsigned short Al[128 * 64];
  __shared__ unsigned short Bl[128 * 64];
  __shared__ int s_item;

  const int xcd0 = blockIdx.x & 7;           // home XCD (round-robin dispatch)

  const int tid  = threadIdx.x;
  const int lane = tid & 63;
  const int wave = tid >> 6;
  const int wr = wave >> 1;
  const int wc = wave & 1;

  const int lr = lane >> 3;
  const int lc = lane & 7;
  const int sc = (lc ^ lr) * 8;        // inverse-swizzled source k-offset
  const int qq   = lane >> 4;
  const int ln15 = lane & 15;
  const int swz  = ln15 & 7;

  int sx = 0;                          // steal cursor (tid 0 only)
  for (;;) {
    if (tid == 0) {
      int it = -1;
      while (sx < 8) {                 // own queue first, then steal
        int x = (xcd0 + sx) & 7;
        int j = atomicAdd(&qc[x], 1);
        if (j < qn[x]) { it = wl[x * QCAP + j]; break; }
        ++sx;                          // queue drained; never revisit
      }
      s_item = it;
    }
    __syncthreads();
    const int v = s_item;
    if (v < 0) return;                 // uniform exit

    const int e  = (v >> 16) & 0xff;
    const int m0 = ((v >> 8) & 0xff) * 128;
    const int n0 = (v & 0xff) * 128;
    const int count = cnt[e];
    const int o     = offv[e];

    const unsigned short* aptr[4];
    const unsigned short* bptr[4];
#pragma unroll
    for (int ii = 0; ii < 4; ++ii) {
      int i = wave * 4 + ii;
      int r = i * 8 + lr;
      int m = m0 + r; if (m > count - 1) m = count - 1;
      size_t arow = GATHER ? (size_t)tok[o + m] : (size_t)(o + m);
      aptr[ii] = Abase + arow * KDIM + sc;
      bptr[ii] = BT + ((size_t)e * NDIM + n0 + r) * KDIM + sc;
    }

    f32x4 acc[4][4];
#pragma unroll
    for (int a = 0; a < 4; ++a)
#pragma unroll
      for (int b = 0; b < 4; ++b) acc[a][b] = 0.f;

    for (int k0 = 0; k0 < KDIM; k0 += 64) {
#pragma unroll
      for (int ii = 0; ii < 4; ++ii) {
        int i = wave * 4 + ii;
        glds16(aptr[ii] + k0, &Al[i * 512]);
        glds16(bptr[ii] + k0, &Bl[i * 512]);
      }
      __syncthreads();
#pragma unroll
      for (int kk = 0; kk < 2; ++kk) {
        bf16x8 af[4], bg[4];
        const int ch = (kk * 4 + qq) ^ swz;
#pragma unroll
        for (int a = 0; a < 4; ++a) {
          int r = wr * 64 + a * 16 + ln15;
          af[a] = *(const bf16x8*)(&Al[r * 64 + ch * 8]);
        }
#pragma unroll
        for (int b = 0; b < 4; ++b) {
          int r = wc * 64 + b * 16 + ln15;
          bg[b] = *(const bf16x8*)(&Bl[r * 64 + ch * 8]);
        }
#pragma unroll
        for (int a = 0; a < 4; ++a)
#pragma unroll
          for (int b = 0; b < 4; ++b)
            acc[a][b] = __builtin_amdgcn_mfma_f32_16x16x32_bf16(af[a], bg[b], acc[a][b], 0, 0, 0);
      }
      __syncthreads();
    }

    float bn[4];
#pragma unroll
    for (int b = 0; b < 4; ++b)
      bn[b] = bias[(size_t)e * NDIM + n0 + wc * 64 + b * 16 + ln15];

    if (EPI == 0) {
      unsigned short* hout = (unsigned short*)outp;
#pragma unroll
      for (int a = 0; a < 4; ++a)
#pragma unroll
        for (int rg = 0; rg < 4; ++rg) {
          int r = wr * 64 + a * 16 + qq * 4 + rg;
          int m = m0 + r;
          if (m < count) {
            size_t slot = (size_t)(o + m);
#pragma unroll
            for (int b = 0; b < 4; ++b) {
              float v2 = acc[a][b][rg] + bn[b];
              v2 = v2 > 0.f ? v2 : 0.f;
              hout[slot * NDIM + n0 + wc * 64 + b * 16 + ln15] = f2bf(v2);
            }
          }
        }
    } else {
      float* obase = (float*)outp;
#pragma unroll
      for (int a = 0; a < 4; ++a)
#pragma unroll
        for (int rg = 0; rg < 4; ++rg) {
          int r = wr * 64 + a * 16 + qq * 4 + rg;
          int m = m0 + r;
          if (m < count) {
            int slot = o + m;
            int tk = tok[slot];
            float w = wtl[slot];
#pragma unroll
            for (int b = 0; b < 4; ++b) {
              float v2 = (acc[a][b][rg] + bn[b]) * w;
              atomicAdd(&obase[(size_t)tk * NDIM + n0 + wc * 64 + b * 16 + ln15], v2);
            }
          }
        }
    }
    // s_item rewritten only by tid 0 after it re-enters the loop; K-loop
    // barriers guarantee every wave has read v before that.
  }
}

// ---------------- launch ----------------------------------------------------
extern "C" void kernel_launch(void* const* d_in, const int* in_sizes, int n_in,
                              void* d_out, int out_size, void* d_ws, size_t ws_size,
                              hipStream_t stream) {
  const float* x  = (const float*)d_in[0];
  const float* Wg = (const float*)d_in[1];
  const float* W1 = (const float*)d_in[2];
  const float* b1 = (const float*)d_in[3];
  const float* W2 = (const float*)d_in[4];
  const float* b2 = (const float*)d_in[5];

  constexpr size_t OFF_CNT  = 0;
  constexpr size_t OFF_OFF  = 256;
  constexpr size_t OFF_QN1  = 512;
  constexpr size_t OFF_QN2  = 544;
  constexpr size_t OFF_QC1  = 576;
  constexpr size_t OFF_QC2  = 608;
  constexpr size_t OFF_WL1  = 4096;
  constexpr size_t OFF_WL2  = OFF_WL1 + (size_t)8 * QCAP1 * 4;   // +64 KB
  constexpr size_t OFF_EIDX = OFF_WL2 + (size_t)8 * QCAP2 * 4;   // +32 KB
  constexpr size_t OFF_EWT  = OFF_EIDX + (size_t)NTOK * 2 * 4;
  constexpr size_t OFF_TOK  = OFF_EWT  + (size_t)NTOK * 2 * 4;
  constexpr size_t OFF_WTL  = OFF_TOK  + (size_t)NTOK * 2 * 4;
  constexpr size_t OFF_XB   = (size_t)1 << 20;
  constexpr size_t OFF_W1T  = OFF_XB  + (size_t)NTOK * DM * 2;
  constexpr size_t OFF_W2T  = OFF_W1T + (size_t)NE * DM * DH * 2;
  constexpr size_t OFF_H    = OFF_W2T + (size_t)NE * DH * DM * 2;
  constexpr size_t REQ      = OFF_H   + (size_t)NTOK * 2 * DH * 2;
  static_assert(OFF_WTL + (size_t)NTOK * 2 * 4 <= OFF_XB, "ws layout overlap");

  if (ws_size < REQ) {
    hipMemsetAsync(d_out, 0, (size_t)out_size * 4, stream);
    return;
  }

  char* ws = (char*)d_ws;
  int*   cnt    = (int*)(ws + OFF_CNT);
  int*   offv   = (int*)(ws + OFF_OFF);
  int*   qn1    = (int*)(ws + OFF_QN1);
  int*   qn2    = (int*)(ws + OFF_QN2);
  int*   qc1    = (int*)(ws + OFF_QC1);
  int*   qc2    = (int*)(ws + OFF_QC2);
  int*   wl1    = (int*)(ws + OFF_WL1);
  int*   wl2    = (int*)(ws + OFF_WL2);
  int*   eidx   = (int*)(ws + OFF_EIDX);
  float* ewt    = (float*)(ws + OFF_EWT);
  int*   tok    = (int*)(ws + OFF_TOK);
  float* wtl    = (float*)(ws + OFF_WTL);
  unsigned short* xb   = (unsigned short*)(ws + OFF_XB);
  unsigned short* w1t  = (unsigned short*)(ws + OFF_W1T);
  unsigned short* w2t  = (unsigned short*)(ws + OFF_W2T);
  unsigned short* hbuf = (unsigned short*)(ws + OFF_H);

  // router (x -> bf16, top-2 weights; also zeroes d_out for GEMM2 atomics)
  router_kernel<<<NTOK / 4, 256, 0, stream>>>(x, Wg, xb, eidx, ewt,
                                              (float*)d_out);
  // plan (block 0) runs concurrently with both weight transposes
  planprep_kernel<<<4097, 1024, 0, stream>>>(
      eidx, ewt, cnt, offv, tok, wtl, wl1, wl2, qn1, qn2, qc1, qc2,
      W1, w1t, W2, w2t);

  // GEMM1: h = relu(x @ W1 + b1), gathered rows, K=1024, N=2048
  gemm_kernel<1, 0, DM, DH, QCAP1><<<NWRK, 256, 0, stream>>>(
      xb, w1t, b1, cnt, offv, tok, wtl, wl1, qn1, qc1, hbuf);
  // GEMM2: out[tok] += (h @ W2 + b2) * w, K=2048, N=1024
  gemm_kernel<0, 1, DH, DM, QCAP2><<<NWRK, 256, 0, stream>>>(
      hbuf, w2t, b2, cnt, offv, tok, wtl, wl2, qn2, qc2, (float*)d_out);
}

// Round 11
// 341.142 us; speedup vs baseline: 3.2081x; 3.2081x over previous
//
#include <hip/hip_runtime.h>
#include <hip/hip_bf16.h>
#include <stdint.h>

#define NTOK 8192
#define DM   1024
#define DH   2048
#define NE   16

// Persistent-worker geometry: 256 CUs x 3 blocks/CU (reg-limited). Per-XCD
// work queues, own-queue only (verified round-3/6/8 config, ~141 us/GEMM).
// NOTE (r9/r10 post-mortem): cross-XCD stealing is twice-falsified here —
// r9 (256-tile, structural) and r10 (steal cursor in the acquisition path
// quadrupled per-item time, MfmaUtil 21%->5.4%). Keep own-queue-only.
#define NWRK  768
#define QCAP1 2048   // worst case per XCD: 128 m-tiles * 16 panels
#define QCAP2 1024   // 128 m-tiles * 8 panels

typedef float  f32x4  __attribute__((ext_vector_type(4)));
typedef __bf16 bf16x8 __attribute__((ext_vector_type(8)));

__device__ __forceinline__ unsigned short f2bf(float f) {
  union { __bf16 b; unsigned short u; } c; c.b = (__bf16)f; return c.u;
}

__device__ __forceinline__ void glds16(const void* g, void* l) {
  __builtin_amdgcn_global_load_lds(
      (const __attribute__((address_space(1))) void*)g,
      (__attribute__((address_space(3))) void*)l, 16, 0, 0);
}

// ---------------- router: logits, top-2, softmax; x -> bf16; zero d_out.
__global__ __launch_bounds__(256) void router_kernel(
    const float* __restrict__ x, const float* __restrict__ Wg,
    unsigned short* __restrict__ xb, int* __restrict__ eidx,
    float* __restrict__ ewt, float* __restrict__ outz)
{
  const int lane = threadIdx.x & 63;
  const int wave = threadIdx.x >> 6;
  const int t = blockIdx.x * 4 + wave;
  const float* xr = x + (size_t)t * DM;

  float4 xv[4];
#pragma unroll
  for (int c = 0; c < 4; ++c)
    xv[c] = *(const float4*)(xr + c * 256 + lane * 4);

  unsigned short* xbr = xb + (size_t)t * DM;
#pragma unroll
  for (int c = 0; c < 4; ++c) {
    ushort4 u;
    u.x = f2bf(xv[c].x); u.y = f2bf(xv[c].y);
    u.z = f2bf(xv[c].z); u.w = f2bf(xv[c].w);
    *(ushort4*)(xbr + c * 256 + lane * 4) = u;
  }

  // zero the atomic target (replaces the hipMemsetAsync dispatch; stream
  // order guarantees completion before GEMM2's atomics)
  {
    float4 z4 = {0.f, 0.f, 0.f, 0.f};
    float* orow = outz + (size_t)t * DM;
#pragma unroll
    for (int c = 0; c < 4; ++c)
      *(float4*)(orow + c * 256 + lane * 4) = z4;
  }

  float acc[NE];
#pragma unroll
  for (int e = 0; e < NE; ++e) acc[e] = 0.f;
#pragma unroll
  for (int e = 0; e < NE; ++e) {
#pragma unroll
    for (int c = 0; c < 4; ++c) {
      float4 wv = *(const float4*)(Wg + e * DM + c * 256 + lane * 4);
      acc[e] += xv[c].x * wv.x + xv[c].y * wv.y + xv[c].z * wv.z + xv[c].w * wv.w;
    }
  }
#pragma unroll
  for (int e = 0; e < NE; ++e) {
    float v = acc[e];
    v += __shfl_xor(v, 1);  v += __shfl_xor(v, 2);  v += __shfl_xor(v, 4);
    v += __shfl_xor(v, 8);  v += __shfl_xor(v, 16); v += __shfl_xor(v, 32);
    acc[e] = v;
  }
  if (lane == 0) {
    float v0 = -1e30f; int i0 = 0;
#pragma unroll
    for (int e = 0; e < NE; ++e) if (acc[e] > v0) { v0 = acc[e]; i0 = e; }
    float v1 = -1e30f; int i1 = 0;
#pragma unroll
    for (int e = 0; e < NE; ++e) if (e != i0 && acc[e] > v1) { v1 = acc[e]; i1 = e; }
    float p = expf(v1 - v0);
    float s = 1.f / (1.f + p);
    eidx[2 * t] = i0; eidx[2 * t + 1] = i1;
    ewt[2 * t] = s;   ewt[2 * t + 1] = p * s;
  }
}

// ---------------- fused plan + weight prep ----------------------------------
// Block 0 (1024 thr): plan. Blocks 1..4096: weight prep fp32 [E][K][N] ->
// bf16 [E][N][K], 4 64x64 tiles per block. plan's serial scan hides under
// the BW-bound transposes. wl1/wl2: expert-outer, m-half (h0 split), panel,
// m-in-half ordering; item (e<<16)|(mt<<8)|p.  [verified round-8 form]
__global__ __launch_bounds__(1024) void planprep_kernel(
    const int* __restrict__ eidx, const float* __restrict__ ewt,
    int* __restrict__ cnt, int* __restrict__ offv,
    int* __restrict__ tok, float* __restrict__ wtl,
    int* __restrict__ wl1, int* __restrict__ wl2,
    int* __restrict__ qn1, int* __restrict__ qn2,
    int* __restrict__ qc1, int* __restrict__ qc2,
    const float* __restrict__ W1, unsigned short* __restrict__ w1t,
    const float* __restrict__ W2, unsigned short* __restrict__ w2t)
{
  __shared__ float t[4][64][68];
  __shared__ int wcnt[16][NE];
  __shared__ int wbase[16][NE];
  __shared__ int offs[NE];
  __shared__ int s_nmt[NE];
  __shared__ int s_pnmt[NE + 1];

  if (blockIdx.x != 0) {
    // ---- weight prep: 4 tiles per 1024-thread block
    const int idx = blockIdx.x - 1;
    const int tg  = threadIdx.x >> 8;     // tile group 0..3
    const int t8  = threadIdx.x & 255;
    const float* W; unsigned short* WT; int K, N, tt, bx, by;
    if (idx < 2048) {
      W = W1; WT = w1t; K = DM; N = DH;
      tt = idx * 4 + tg;                  // 0..8191
      int r = tt & 511; bx = r & 31; by = r >> 5;
    } else {
      W = W2; WT = w2t; K = DH; N = DM;
      tt = (idx - 2048) * 4 + tg;
      int r = tt & 511; bx = r & 15; by = r >> 4;
    }
    const int bz = tt >> 9;
    const int k0 = by * 64, n0 = bx * 64;
    const int tr = t8 >> 2;
    const int tc = (t8 & 3) * 16;
    const float* src = W + ((size_t)bz * K + k0) * N + n0;
#pragma unroll
    for (int j = 0; j < 4; ++j) {
      float4 v = *(const float4*)(src + (size_t)tr * N + tc + j * 4);
      t[tg][tc + j * 4 + 0][tr] = v.x;
      t[tg][tc + j * 4 + 1][tr] = v.y;
      t[tg][tc + j * 4 + 2][tr] = v.z;
      t[tg][tc + j * 4 + 3][tr] = v.w;
    }
    __syncthreads();
    unsigned short* dst = WT + ((size_t)bz * N + n0) * K + k0;
#pragma unroll
    for (int j = 0; j < 4; ++j) {
      float4 v = *(const float4*)(&t[tg][tr][tc + j * 4]);
      ushort4 u;
      u.x = f2bf(v.x); u.y = f2bf(v.y); u.z = f2bf(v.z); u.w = f2bf(v.w);
      *(ushort4*)(dst + (size_t)tr * K + tc + j * 4) = u;
    }
    return;
  }

  // ---- plan (block 0, 1024 threads)
  const int tid  = threadIdx.x;
  const int wave = tid >> 6;
  const int lane = tid & 63;
  const unsigned long long below = (1ull << lane) - 1ull;

  // phase 1: cache pairs; per-wave per-expert counts via ballot
  int   pe[16];
  float pw[16];
  int   count[NE];
#pragma unroll
  for (int e = 0; e < NE; ++e) count[e] = 0;
#pragma unroll
  for (int r = 0; r < 16; ++r) {
    int p = wave * 1024 + r * 64 + lane;
    pe[r] = eidx[p];
    pw[r] = ewt[p];
#pragma unroll
    for (int e = 0; e < NE; ++e) {
      unsigned long long m = __ballot(pe[r] == e);
      count[e] += (int)__popcll(m);
    }
  }
  if (lane == 0) {
#pragma unroll
    for (int e = 0; e < NE; ++e) wcnt[wave][e] = count[e];
  }
  __syncthreads();

  // phase 2: thread 0 serial scan; offsets + tile geometry
  if (tid == 0) {
    int s = 0;
    s_pnmt[0] = 0;
    for (int e = 0; e < NE; ++e) {
      offs[e] = s;
      int tcnt = 0;
      for (int w = 0; w < 16; ++w) { wbase[w][e] = tcnt; tcnt += wcnt[w][e]; }
      cnt[e] = tcnt; offv[e] = s; s += tcnt;
      int nmt = (tcnt + 127) >> 7;
      s_nmt[e] = nmt;
      s_pnmt[e + 1] = s_pnmt[e] + nmt;
    }
    offv[NE] = s;
  }
  __syncthreads();

  // queue sizes + counter reset (one thread per XCD)
  if (tid < 8) {
    qn1[tid] = (s_nmt[tid] + s_nmt[tid + 8]) * 16;
    qn2[tid] = (s_nmt[tid] + s_nmt[tid + 8]) * 8;
    qc1[tid] = 0;
    qc2[tid] = 0;
  }

  // phase 2b: parallel dense queue fill (closed-form bijective positions)
  {
    const int totmt = s_pnmt[NE];
    const int T1 = totmt * 16;
    for (int i = tid; i < T1; i += 1024) {
      int gmt = i >> 4, p = i & 15;
      int e = 0;
      while (s_pnmt[e + 1] <= gmt) ++e;
      int mt  = gmt - s_pnmt[e];
      int nmt = s_nmt[e];
      int h0  = (nmt + 1) >> 1;   // m-half split: hot A slab stays bounded
      int pos_e = (mt < h0) ? (p * h0 + mt)
                            : (h0 * 16 + p * (nmt - h0) + (mt - h0));
      int xx   = e & 7;
      int base = (e < 8) ? 0 : s_nmt[e - 8] * 16;
      wl1[xx * QCAP1 + base + pos_e] = (e << 16) | (mt << 8) | p;
    }
    const int T2 = totmt * 8;
    for (int i = tid; i < T2; i += 1024) {
      int gmt = i >> 3, p = i & 7;
      int e = 0;
      while (s_pnmt[e + 1] <= gmt) ++e;
      int mt  = gmt - s_pnmt[e];
      int nmt = s_nmt[e];
      int h0  = (nmt + 1) >> 1;
      int pos_e = (mt < h0) ? (p * h0 + mt)
                            : (h0 * 8 + p * (nmt - h0) + (mt - h0));
      int xx   = e & 7;
      int base = (e < 8) ? 0 : s_nmt[e - 8] * 8;
      wl2[xx * QCAP2 + base + pos_e] = (e << 16) | (mt << 8) | p;
    }
  }

  // phase 3: rank + scatter tokens (deterministic)
  int run[NE];
#pragma unroll
  for (int e = 0; e < NE; ++e) run[e] = 0;
#pragma unroll
  for (int r = 0; r < 16; ++r) {
    int p = wave * 1024 + r * 64 + lane;
#pragma unroll
    for (int e = 0; e < NE; ++e) {
      unsigned long long m = __ballot(pe[r] == e);
      if (pe[r] == e) {
        int rank = (int)__popcll(m & below);
        int slot = offs[e] + wbase[wave][e] + run[e] + rank;
        tok[slot] = p >> 1;
        wtl[slot] = pw[r];
      }
      run[e] += (int)__popcll(m);
    }
  }
}

// ---------------- 128x128 gathered GEMM, BK=64, m97 2-barrier loop,
// persistent per-XCD workers (own queue only). Verbatim round-3/6/8 kernel.
// EPI=0: h = relu(acc+b1) -> bf16    EPI=1: atomicAdd(out, (acc+b2)*w)
template<int GATHER, int EPI, int KDIM, int NDIM, int QCAP>
__global__ __launch_bounds__(256, 3) void gemm_kernel(
    const unsigned short* __restrict__ Abase,
    const unsigned short* __restrict__ BT,
    const float* __restrict__ bias,
    const int* __restrict__ cnt, const int* __restrict__ offv,
    const int* __restrict__ tok, const float* __restrict__ wtl,
    const int* __restrict__ wl, const int* __restrict__ qn,
    int* __restrict__ qc, void* __restrict__ outp)
{
  __shared__ unsigned short Al[128 * 64];
  __shared__ unsigned short Bl[128 * 64];
  __shared__ int s_j;

  const int xcd = blockIdx.x & 7;            // round-robin dispatch -> XCD id
  const int* q_ = wl + xcd * QCAP;
  const int myqn = qn[xcd];

  const int tid  = threadIdx.x;
  const int lane = tid & 63;
  const int wave = tid >> 6;
  const int wr = wave >> 1;
  const int wc = wave & 1;

  const int lr = lane >> 3;
  const int lc = lane & 7;
  const int sc = (lc ^ lr) * 8;        // inverse-swizzled source k-offset
  const int qq   = lane >> 4;
  const int ln15 = lane & 15;
  const int swz  = ln15 & 7;

  for (;;) {
    if (tid == 0) s_j = atomicAdd(&qc[xcd], 1);
    __syncthreads();
    const int j = s_j;
    if (j >= myqn) return;                   // uniform exit
    const int v = q_[j];

    const int e  = (v >> 16) & 0xff;
    const int m0 = ((v >> 8) & 0xff) * 128;
    const int n0 = (v & 0xff) * 128;
    const int count = cnt[e];
    const int o     = offv[e];

    const unsigned short* aptr[4];
    const unsigned short* bptr[4];
#pragma unroll
    for (int ii = 0; ii < 4; ++ii) {
      int i = wave * 4 + ii;
      int r = i * 8 + lr;
      int m = m0 + r; if (m > count - 1) m = count - 1;
      size_t arow = GATHER ? (size_t)tok[o + m] : (size_t)(o + m);
      aptr[ii] = Abase + arow * KDIM + sc;
      bptr[ii] = BT + ((size_t)e * NDIM + n0 + r) * KDIM + sc;
    }

    f32x4 acc[4][4];
#pragma unroll
    for (int a = 0; a < 4; ++a)
#pragma unroll
      for (int b = 0; b < 4; ++b) acc[a][b] = 0.f;

    for (int k0 = 0; k0 < KDIM; k0 += 64) {
#pragma unroll
      for (int ii = 0; ii < 4; ++ii) {
        int i = wave * 4 + ii;
        glds16(aptr[ii] + k0, &Al[i * 512]);
        glds16(bptr[ii] + k0, &Bl[i * 512]);
      }
      __syncthreads();
#pragma unroll
      for (int kk = 0; kk < 2; ++kk) {
        bf16x8 af[4], bg[4];
        const int ch = (kk * 4 + qq) ^ swz;
#pragma unroll
        for (int a = 0; a < 4; ++a) {
          int r = wr * 64 + a * 16 + ln15;
          af[a] = *(const bf16x8*)(&Al[r * 64 + ch * 8]);
        }
#pragma unroll
        for (int b = 0; b < 4; ++b) {
          int r = wc * 64 + b * 16 + ln15;
          bg[b] = *(const bf16x8*)(&Bl[r * 64 + ch * 8]);
        }
#pragma unroll
        for (int a = 0; a < 4; ++a)
#pragma unroll
          for (int b = 0; b < 4; ++b)
            acc[a][b] = __builtin_amdgcn_mfma_f32_16x16x32_bf16(af[a], bg[b], acc[a][b], 0, 0, 0);
      }
      __syncthreads();
    }

    float bn[4];
#pragma unroll
    for (int b = 0; b < 4; ++b)
      bn[b] = bias[(size_t)e * NDIM + n0 + wc * 64 + b * 16 + ln15];

    if (EPI == 0) {
      unsigned short* hout = (unsigned short*)outp;
#pragma unroll
      for (int a = 0; a < 4; ++a)
#pragma unroll
        for (int rg = 0; rg < 4; ++rg) {
          int r = wr * 64 + a * 16 + qq * 4 + rg;
          int m = m0 + r;
          if (m < count) {
            size_t slot = (size_t)(o + m);
#pragma unroll
            for (int b = 0; b < 4; ++b) {
              float v2 = acc[a][b][rg] + bn[b];
              v2 = v2 > 0.f ? v2 : 0.f;
              hout[slot * NDIM + n0 + wc * 64 + b * 16 + ln15] = f2bf(v2);
            }
          }
        }
    } else {
      float* obase = (float*)outp;
#pragma unroll
      for (int a = 0; a < 4; ++a)
#pragma unroll
        for (int rg = 0; rg < 4; ++rg) {
          int r = wr * 64 + a * 16 + qq * 4 + rg;
          int m = m0 + r;
          if (m < count) {
            int slot = o + m;
            int tk = tok[slot];
            float w = wtl[slot];
#pragma unroll
            for (int b = 0; b < 4; ++b) {
              float v2 = (acc[a][b][rg] + bn[b]) * w;
              atomicAdd(&obase[(size_t)tk * NDIM + n0 + wc * 64 + b * 16 + ln15], v2);
            }
          }
        }
    }
    // s_j rewritten only by tid 0 after it re-enters the loop; K-loop
    // barriers guarantee every wave has read j before that.
  }
}

// ---------------- launch ----------------------------------------------------
extern "C" void kernel_launch(void* const* d_in, const int* in_sizes, int n_in,
                              void* d_out, int out_size, void* d_ws, size_t ws_size,
                              hipStream_t stream) {
  const float* x  = (const float*)d_in[0];
  const float* Wg = (const float*)d_in[1];
  const float* W1 = (const float*)d_in[2];
  const float* b1 = (const float*)d_in[3];
  const float* W2 = (const float*)d_in[4];
  const float* b2 = (const float*)d_in[5];

  constexpr size_t OFF_CNT  = 0;
  constexpr size_t OFF_OFF  = 256;
  constexpr size_t OFF_QN1  = 512;
  constexpr size_t OFF_QN2  = 544;
  constexpr size_t OFF_QC1  = 576;
  constexpr size_t OFF_QC2  = 608;
  constexpr size_t OFF_WL1  = 4096;
  constexpr size_t OFF_WL2  = OFF_WL1 + (size_t)8 * QCAP1 * 4;   // +64 KB
  constexpr size_t OFF_EIDX = OFF_WL2 + (size_t)8 * QCAP2 * 4;   // +32 KB
  constexpr size_t OFF_EWT  = OFF_EIDX + (size_t)NTOK * 2 * 4;
  constexpr size_t OFF_TOK  = OFF_EWT  + (size_t)NTOK * 2 * 4;
  constexpr size_t OFF_WTL  = OFF_TOK  + (size_t)NTOK * 2 * 4;
  constexpr size_t OFF_XB   = (size_t)1 << 20;
  constexpr size_t OFF_W1T  = OFF_XB  + (size_t)NTOK * DM * 2;
  constexpr size_t OFF_W2T  = OFF_W1T + (size_t)NE * DM * DH * 2;
  constexpr size_t OFF_H    = OFF_W2T + (size_t)NE * DH * DM * 2;
  constexpr size_t REQ      = OFF_H   + (size_t)NTOK * 2 * DH * 2;
  static_assert(OFF_WTL + (size_t)NTOK * 2 * 4 <= OFF_XB, "ws layout overlap");

  if (ws_size < REQ) {
    hipMemsetAsync(d_out, 0, (size_t)out_size * 4, stream);
    return;
  }

  char* ws = (char*)d_ws;
  int*   cnt    = (int*)(ws + OFF_CNT);
  int*   offv   = (int*)(ws + OFF_OFF);
  int*   qn1    = (int*)(ws + OFF_QN1);
  int*   qn2    = (int*)(ws + OFF_QN2);
  int*   qc1    = (int*)(ws + OFF_QC1);
  int*   qc2    = (int*)(ws + OFF_QC2);
  int*   wl1    = (int*)(ws + OFF_WL1);
  int*   wl2    = (int*)(ws + OFF_WL2);
  int*   eidx   = (int*)(ws + OFF_EIDX);
  float* ewt    = (float*)(ws + OFF_EWT);
  int*   tok    = (int*)(ws + OFF_TOK);
  float* wtl    = (float*)(ws + OFF_WTL);
  unsigned short* xb   = (unsigned short*)(ws + OFF_XB);
  unsigned short* w1t  = (unsigned short*)(ws + OFF_W1T);
  unsigned short* w2t  = (unsigned short*)(ws + OFF_W2T);
  unsigned short* hbuf = (unsigned short*)(ws + OFF_H);

  // router (x -> bf16, top-2 weights; also zeroes d_out for GEMM2 atomics)
  router_kernel<<<NTOK / 4, 256, 0, stream>>>(x, Wg, xb, eidx, ewt,
                                              (float*)d_out);
  // plan (block 0) runs concurrently with both weight transposes
  planprep_kernel<<<4097, 1024, 0, stream>>>(
      eidx, ewt, cnt, offv, tok, wtl, wl1, wl2, qn1, qn2, qc1, qc2,
      W1, w1t, W2, w2t);

  // GEMM1: h = relu(x @ W1 + b1), gathered rows, K=1024, N=2048
  gemm_kernel<1, 0, DM, DH, QCAP1><<<NWRK, 256, 0, stream>>>(
      xb, w1t, b1, cnt, offv, tok, wtl, wl1, qn1, qc1, hbuf);
  // GEMM2: out[tok] += (h @ W2 + b2) * w, K=2048, N=1024
  gemm_kernel<0, 1, DH, DM, QCAP2><<<NWRK, 256, 0, stream>>>(
      hbuf, w2t, b2, cnt, offv, tok, wtl, wl2, qn2, qc2, (float*)d_out);
}